// Round 1
// baseline (4737.088 us; speedup 1.0000x reference)
//
#include <hip/hip_runtime.h>

// ---------------------------------------------------------------------------
// Self_RNN forward, MI355X.
// Math (derived from reference):
//   Wrv = Wrec@Wv ; Wrk = Wrec@Wk ; Wrq = Wrec@Wq ; Wkq = Wrk@Wrq^T
//   WgT = Wrk@Wq^T  (so G = x@Wg with Wg = Wq@Wrk^T)
//   G[b,t]  = x[b,t] @ Wg   (for scores s1,s2 = h.G)
//   XV[b,t] = x[b,t] @ Wv
//   per step: y = h @ [Wrv | Wkq]  -> Vh = y[0:512], q = y[512:1024]
//             s0 = (q.h)*sc, s1 = (h.G[t-1])*sc, s2 = (h.G[t])*sc
//             a = softmax(s0,s1,s2); h = a0*Vh + a1*XV[t-1] + a2*XV[t]
// ---------------------------------------------------------------------------

typedef _Float16 f16;
typedef _Float16 half8 __attribute__((ext_vector_type(8)));
typedef _Float16 half2v __attribute__((ext_vector_type(2)));
typedef float floatx4 __attribute__((ext_vector_type(4)));

#define AM_F32 0
#define AM_F16 1
#define BM_NN_F32 0   // B  is [K][N] f32 (transpose-staged)
#define BM_BT_F16 1   // Bt is [N][K] f16
#define BM_BT_F32 2   // Bt is [N][K] f32

// C[M,N] (f16, ldc/coff) = A[M,K] @ B ; 128x128 tile, BK=32, 4 waves, MFMA f16.
template<int AMODE, int BMODE>
__global__ __launch_bounds__(256)
void gemm128(const void* __restrict__ Ap, const void* __restrict__ Bp,
             f16* __restrict__ C, int K, int ldbnn, long ldc, long coff,
             int ntiles) {
  __shared__ f16 Al[128 * 32];
  __shared__ f16 Bl[128 * 32];
  const int tid = threadIdx.x;
  const int lane = tid & 63;
  const int wid = tid >> 6;
  const int wr = wid >> 1, wc = wid & 1;
  const int mt = blockIdx.x / ntiles, nt = blockIdx.x % ntiles;
  const long m0 = (long)mt * 128, n0 = (long)nt * 128;

  floatx4 acc[4][4];
#pragma unroll
  for (int m = 0; m < 4; ++m)
#pragma unroll
    for (int n = 0; n < 4; ++n) acc[m][n] = (floatx4){0.f, 0.f, 0.f, 0.f};

  for (int k0 = 0; k0 < K; k0 += 32) {
    __syncthreads();  // protect LDS from previous iteration's readers
    // ---- stage A tile [128][32] ----
#pragma unroll
    for (int i = 0; i < 2; ++i) {
      const int slot = i * 256 + tid;      // 512 slots x 16B
      const int row = slot >> 2;
      const int kc = (slot & 3) * 8;
      if constexpr (AMODE == AM_F16) {
        const f16* Ag = (const f16*)Ap;
        half8 v = *(const half8*)(Ag + (m0 + row) * (long)K + k0 + kc);
        *(half8*)(Al + slot * 8) = v;
      } else {
        const float* Ag = (const float*)Ap;
        const float* p = Ag + (m0 + row) * (long)K + k0 + kc;
        float4 v0 = *(const float4*)(p);
        float4 v1 = *(const float4*)(p + 4);
        half8 h;
        h[0] = (f16)v0.x; h[1] = (f16)v0.y; h[2] = (f16)v0.z; h[3] = (f16)v0.w;
        h[4] = (f16)v1.x; h[5] = (f16)v1.y; h[6] = (f16)v1.z; h[7] = (f16)v1.w;
        *(half8*)(Al + slot * 8) = h;
      }
    }
    // ---- stage B tile -> Bl[n][k] ----
    if constexpr (BMODE == BM_NN_F32) {
      const float* Bg = (const float*)Bp;
      const int nn = tid & 127;
      const int kh = (tid >> 7) * 16;
#pragma unroll
      for (int j = 0; j < 16; j += 2) {
        float b0 = Bg[(long)(k0 + kh + j) * ldbnn + n0 + nn];
        float b1 = Bg[(long)(k0 + kh + j + 1) * ldbnn + n0 + nn];
        half2v hv; hv[0] = (f16)b0; hv[1] = (f16)b1;
        *(half2v*)(Bl + nn * 32 + kh + j) = hv;
      }
    } else {
#pragma unroll
      for (int i = 0; i < 2; ++i) {
        const int slot = i * 256 + tid;
        const int row = slot >> 2;
        const int kc = (slot & 3) * 8;
        if constexpr (BMODE == BM_BT_F16) {
          const f16* Bg = (const f16*)Bp;
          half8 v = *(const half8*)(Bg + (n0 + row) * (long)K + k0 + kc);
          *(half8*)(Bl + slot * 8) = v;
        } else {
          const float* Bg = (const float*)Bp;
          const float* p = Bg + (n0 + row) * (long)K + k0 + kc;
          float4 v0 = *(const float4*)(p);
          float4 v1 = *(const float4*)(p + 4);
          half8 h;
          h[0] = (f16)v0.x; h[1] = (f16)v0.y; h[2] = (f16)v0.z; h[3] = (f16)v0.w;
          h[4] = (f16)v1.x; h[5] = (f16)v1.y; h[6] = (f16)v1.z; h[7] = (f16)v1.w;
          *(half8*)(Bl + slot * 8) = h;
        }
      }
    }
    __syncthreads();
    // ---- compute: 16 MFMA per K-step per wave ----
    const int frow = lane & 15;
    const int fkc = (lane >> 4) * 8;
    half8 af[4], bf[4];
#pragma unroll
    for (int m = 0; m < 4; ++m)
      af[m] = *(const half8*)(Al + (wr * 64 + m * 16 + frow) * 32 + fkc);
#pragma unroll
    for (int n = 0; n < 4; ++n)
      bf[n] = *(const half8*)(Bl + (wc * 64 + n * 16 + frow) * 32 + fkc);
#pragma unroll
    for (int m = 0; m < 4; ++m)
#pragma unroll
      for (int n = 0; n < 4; ++n)
        acc[m][n] = __builtin_amdgcn_mfma_f32_16x16x32_f16(af[m], bf[n],
                                                           acc[m][n], 0, 0, 0);
  }
  // ---- write C (f16): C/D frag col=lane&15, row=(lane>>4)*4+reg ----
  const int crow = (lane >> 4) * 4;
  const int ccol = lane & 15;
#pragma unroll
  for (int m = 0; m < 4; ++m)
#pragma unroll
    for (int n = 0; n < 4; ++n)
#pragma unroll
      for (int r = 0; r < 4; ++r) {
        long row = m0 + wr * 64 + m * 16 + crow + r;
        long col = coff + n0 + wc * 64 + n * 16 + ccol;
        C[row * ldc + col] = (f16)acc[m][n][r];
      }
}

// Sequential recurrence: one workgroup per batch chain. h lives in LDS (fp32).
// Wseq [512][1024] f16 row-major ([Wrv | Wkq]); GXV [B*T][1024] f16 ([G | XV]).
__global__ __launch_bounds__(512)
void seq_kernel(const f16* __restrict__ Wseq, const f16* __restrict__ GXV,
                float* __restrict__ out, int T) {
  const int b = blockIdx.x;
  const int tid = threadIdx.x;
  __shared__ float hf[512];
  __shared__ float yred[4][1024];
  __shared__ float yv[512];
  __shared__ float swred[3][8];
  __shared__ float svals[3];

  hf[tid] = 0.f;
  __syncthreads();

  const int up = tid >> 7;   // u-partition 0..3 (128 u's each)
  const int cg = tid & 127;  // col-group: cols cg*8 .. cg*8+7
  const f16* wb = Wseq + (size_t)up * 128 * 1024 + cg * 8;
  const float scale = 0.04419417382415922f;  // 1/sqrt(512)

  for (int t = 0; t < T; ++t) {
    // ---- y partial: this thread's 8 cols over its 128 u's ----
    float acc[8];
#pragma unroll
    for (int j = 0; j < 8; ++j) acc[j] = 0.f;
    const float* hbase = hf + up * 128;
#pragma unroll 8
    for (int u = 0; u < 128; ++u) {
      half8 w = *(const half8*)(wb + (size_t)u * 1024);
      float hu = hbase[u];
      acc[0] += hu * (float)w[0]; acc[1] += hu * (float)w[1];
      acc[2] += hu * (float)w[2]; acc[3] += hu * (float)w[3];
      acc[4] += hu * (float)w[4]; acc[5] += hu * (float)w[5];
      acc[6] += hu * (float)w[6]; acc[7] += hu * (float)w[7];
    }
#pragma unroll
    for (int j = 0; j < 8; ++j) yred[up][cg * 8 + j] = acc[j];
    __syncthreads();

    // ---- reduce partials; score partial products ----
    const f16* grow = GXV + ((size_t)b * T + t) * 1024;
    float ya = yred[0][tid] + yred[1][tid] + yred[2][tid] + yred[3][tid];
    float yb = yred[0][tid + 512] + yred[1][tid + 512] + yred[2][tid + 512] +
               yred[3][tid + 512];
    yv[tid] = ya;            // Vh[c]
    float h_c = hf[tid];
    float p0 = yb * h_c;                                   // q.h
    float p2 = h_c * (float)grow[tid];                     // h.G[t]
    float p1 = (t > 0) ? h_c * (float)(grow - 1024)[tid] : 0.f;  // h.G[t-1]
#pragma unroll
    for (int off = 32; off > 0; off >>= 1) {
      p0 += __shfl_down(p0, off);
      p1 += __shfl_down(p1, off);
      p2 += __shfl_down(p2, off);
    }
    const int wv = tid >> 6;
    if ((tid & 63) == 0) { swred[0][wv] = p0; swred[1][wv] = p1; swred[2][wv] = p2; }
    __syncthreads();
    if (tid < 3) {
      float s = 0.f;
#pragma unroll
      for (int i = 0; i < 8; ++i) s += swred[tid][i];
      svals[tid] = s * scale;
    }
    __syncthreads();

    // ---- softmax(3) + h update ----
    float s0 = svals[0], s1 = svals[1], s2 = svals[2];
    float mx = fmaxf(s0, fmaxf(s1, s2));
    float e0 = __expf(s0 - mx), e1 = __expf(s1 - mx), e2 = __expf(s2 - mx);
    float inv = 1.f / (e0 + e1 + e2);
    const f16* xvrow = grow + 512;
    float xvc = (float)xvrow[tid];
    float xvp = (t > 0) ? (float)(xvrow - 1024)[tid] : 0.f;
    float hn = (e0 * yv[tid] + e1 * xvp + e2 * xvc) * inv;
    hf[tid] = hn;  // all hf readers finished before the svals barrier
    __syncthreads();
  }
  out[(size_t)b * 512 + tid] = hf[tid];
}

extern "C" void kernel_launch(void* const* d_in, const int* in_sizes, int n_in,
                              void* d_out, int out_size, void* d_ws,
                              size_t ws_size, hipStream_t stream) {
  const float* x = (const float*)d_in[0];     // [64][512][512]
  const float* Wq = (const float*)d_in[1];    // [512][512]
  const float* Wk = (const float*)d_in[2];
  const float* Wv = (const float*)d_in[3];
  const float* Wrec = (const float*)d_in[4];
  float* out = (float*)d_out;                 // [64][512]

  char* ws = (char*)d_ws;
  f16* GXV = (f16*)ws;                                   // 32768*1024*2 = 64MB
  f16* Wseq = (f16*)(ws + 67108864);                     // 512*1024*2
  f16* Wrk = (f16*)(ws + 67108864 + 1048576);            // 512*512*2
  f16* Wrq = (f16*)(ws + 67108864 + 1048576 + 524288);
  f16* WgT = (f16*)(ws + 67108864 + 1048576 + 1048576);

  // ---- one-time weight combinations (512x512x512 each) ----
  gemm128<AM_F32, BM_NN_F32><<<16, 256, 0, stream>>>(Wrec, Wk, Wrk, 512, 512, 512, 0, 4);
  gemm128<AM_F32, BM_NN_F32><<<16, 256, 0, stream>>>(Wrec, Wq, Wrq, 512, 512, 512, 0, 4);
  // Wrv -> Wseq[:, 0:512]
  gemm128<AM_F32, BM_NN_F32><<<16, 256, 0, stream>>>(Wrec, Wv, Wseq, 512, 512, 1024, 0, 4);
  // Wkq = Wrk @ Wrq^T -> Wseq[:, 512:1024]
  gemm128<AM_F16, BM_BT_F16><<<16, 256, 0, stream>>>(Wrk, Wrq, Wseq, 512, 0, 1024, 512, 4);
  // WgT = Wrk @ Wq^T
  gemm128<AM_F16, BM_BT_F32><<<16, 256, 0, stream>>>(Wrk, Wq, WgT, 512, 0, 512, 0, 4);
  // ---- big precompute: G and XV for all (b,t)  (M=32768, N=512 each) ----
  gemm128<AM_F32, BM_BT_F16><<<1024, 256, 0, stream>>>(x, WgT, GXV, 512, 0, 1024, 0, 4);
  gemm128<AM_F32, BM_NN_F32><<<1024, 256, 0, stream>>>(x, Wv, GXV, 512, 512, 1024, 512, 4);

  // ---- sequential recurrence: one WG per batch chain ----
  seq_kernel<<<64, 512, 0, stream>>>(Wseq, GXV, out, 512);
}